// Round 1
// baseline (535.744 us; speedup 1.0000x reference)
//
#include <hip/hip_runtime.h>
#include <math.h>

#define N_ANCH 49104
#define NCLS 80
#define KDET 100
#define CAP 2048      // max candidates staged per chunk (top bins hold ~48 each -> chunk ~2000)
#define NBINS 1024
#define TPB 256
#define TROWS 128

// ---------------- transpose [N,C] -> [C,N] so per-class reads are coalesced ----------------
__global__ __launch_bounds__(256) void transpose_scores(const float* __restrict__ scores,
                                                        float* __restrict__ st) {
    __shared__ float tile[TROWS][NCLS + 1];   // +1 pad: column reads hit distinct banks
    const int n0 = blockIdx.x * TROWS;
    for (int i = threadIdx.x; i < TROWS * NCLS; i += blockDim.x) {
        int j = i / NCLS, c = i - j * NCLS;   // consecutive i == consecutive memory -> coalesced
        int n = n0 + j;
        tile[j][c] = (n < N_ANCH) ? scores[(size_t)n * NCLS + c] : -1.0f;
    }
    __syncthreads();
    for (int i = threadIdx.x; i < TROWS * NCLS; i += blockDim.x) {
        int c = i / TROWS, j = i - c * TROWS; // consecutive threads -> consecutive n -> coalesced
        int n = n0 + j;
        if (n < N_ANCH) st[(size_t)c * N_ANCH + n] = tile[j][c];
    }
}

// ---------------- one block per class: histogram-chunked greedy NMS ----------------
__global__ __launch_bounds__(TPB) void nms_kernel(const float* __restrict__ sc_base,
                                                  int sc_stride, int transposed,
                                                  const float* __restrict__ boxes,
                                                  float* __restrict__ out) {
    const int c = blockIdx.x;
    const int tid = threadIdx.x;
    const float* col = transposed ? (sc_base + (size_t)c * N_ANCH) : (sc_base + c);

    __shared__ int   hist[NBINS];
    __shared__ float cs[CAP];                 // candidate score (-inf once suppressed)
    __shared__ int   ci[CAP];                 // candidate anchor index (for argmax tie-break)
    __shared__ float cbx[CAP], cby[CAP], cbX[CAP], cbY[CAP], car[CAP];
    __shared__ float kx1[KDET], ky1[KDET], kx2[KDET], ky2[KDET], kar[KDET], ksc[KDET];
    __shared__ int   s_cnt, s_lo, s_bi;
    __shared__ float s_bv;
    __shared__ float red_v[TPB / 64];
    __shared__ int   red_i[TPB / 64], red_a[TPB / 64];

    // ---- pass 1: score histogram (only scores > 0.05 counted) ----
    for (int b = tid; b < NBINS; b += TPB) hist[b] = 0;
    __syncthreads();
    for (int n = tid; n < N_ANCH; n += TPB) {
        float s = col[(size_t)n * sc_stride];
        if (s > 0.05f) {
            int b = (int)(s * (float)NBINS);
            b = b < 0 ? 0 : (b > NBINS - 1 ? NBINS - 1 : b);
            atomicAdd(&hist[b], 1);
        }
    }
    __syncthreads();

    int kc = 0;        // kept so far (uniform across block)
    int hi = NBINS;    // process score bins [lo, hi) per chunk, top-down
    while (hi > 0 && kc < KDET) {
        if (tid == 0) {
            int lo = hi, tot = 0;
            while (lo > 0 && tot + hist[lo - 1] <= CAP) { lo--; tot += hist[lo]; }
            if (lo == hi) lo = hi - 1;   // oversized single bin: truncate (max bin ~100 here, never hit)
            s_lo = lo;
            s_cnt = 0;
        }
        __syncthreads();
        const int lo = s_lo;

        // ---- collect chunk candidates into LDS ----
        for (int n = tid; n < N_ANCH; n += TPB) {
            float s = col[(size_t)n * sc_stride];
            if (s > 0.05f) {
                int b = (int)(s * (float)NBINS);
                b = b < 0 ? 0 : (b > NBINS - 1 ? NBINS - 1 : b);
                if (b >= lo && b < hi) {
                    int p = atomicAdd(&s_cnt, 1);
                    if (p < CAP) {
                        cs[p] = s; ci[p] = n;
                        float4 bx = *(const float4*)(boxes + (size_t)n * 4);
                        cbx[p] = bx.x; cby[p] = bx.y; cbX[p] = bx.z; cbY[p] = bx.w;
                        car[p] = (bx.z - bx.x) * (bx.w - bx.y);
                    }
                }
            }
        }
        __syncthreads();
        const int M = min(s_cnt, CAP);

        // ---- drop new candidates already suppressed by kept boxes (chunk continuation) ----
        for (int t = tid; t < M; t += TPB) {
            float x1 = cbx[t], y1 = cby[t], x2 = cbX[t], y2 = cbY[t], ar = car[t];
            float sv = cs[t];
            for (int kb = 0; kb < kc; kb++) {
                float ix1 = fmaxf(kx1[kb], x1), iy1 = fmaxf(ky1[kb], y1);
                float ix2 = fminf(kx2[kb], x2), iy2 = fminf(ky2[kb], y2);
                float inter = fmaxf(ix2 - ix1, 0.0f) * fmaxf(iy2 - iy1, 0.0f);
                float iou = inter / (kar[kb] + ar - inter + 1e-8f);
                if (iou > 0.5f) { sv = -INFINITY; break; }
            }
            cs[t] = sv;
        }
        __syncthreads();

        // ---- greedy selection rounds within chunk ----
        while (kc < KDET) {
            // block-wide argmax over cs[0..M), tie-break = lowest anchor index (jnp.argmax semantics)
            float bv = -INFINITY; int bi = -1, ba = 0x7fffffff;
            for (int t = tid; t < M; t += TPB) {
                float v = cs[t];
                int a = ci[t];
                if (v > bv || (v == bv && a < ba)) { bv = v; bi = t; ba = a; }
            }
            for (int off = 32; off > 0; off >>= 1) {
                float ov = __shfl_down(bv, off, 64);
                int   oi = __shfl_down(bi, off, 64);
                int   oa = __shfl_down(ba, off, 64);
                if (ov > bv || (ov == bv && oa < ba)) { bv = ov; bi = oi; ba = oa; }
            }
            if ((tid & 63) == 0) { red_v[tid >> 6] = bv; red_i[tid >> 6] = bi; red_a[tid >> 6] = ba; }
            __syncthreads();
            if (tid == 0) {
                float fv = red_v[0]; int fi = red_i[0]; int fa = red_a[0];
                for (int w = 1; w < TPB / 64; w++) {
                    if (red_v[w] > fv || (red_v[w] == fv && red_a[w] < fa)) {
                        fv = red_v[w]; fi = red_i[w]; fa = red_a[w];
                    }
                }
                s_bv = fv; s_bi = fi;
            }
            __syncthreads();
            const int sel = s_bi;
            if (sel < 0) break;   // chunk exhausted (all -inf); fetch next chunk
            const float bx1 = cbx[sel], by1 = cby[sel], bx2 = cbX[sel], by2 = cbY[sel];
            const float bar = car[sel];
            if (tid == 0) {
                kx1[kc] = bx1; ky1[kc] = by1; kx2[kc] = bx2; ky2[kc] = by2;
                kar[kc] = bar; ksc[kc] = s_bv;
            }
            kc++;
            // suppress: IoU(selected, candidate) > 0.5 (selected suppresses itself: IoU = 1)
            for (int t = tid; t < M; t += TPB) {
                float ix1 = fmaxf(bx1, cbx[t]), iy1 = fmaxf(by1, cby[t]);
                float ix2 = fminf(bx2, cbX[t]), iy2 = fminf(by2, cbY[t]);
                float inter = fmaxf(ix2 - ix1, 0.0f) * fmaxf(iy2 - iy1, 0.0f);
                float iou = inter / (bar + car[t] - inter + 1e-8f);
                if (iou > 0.5f) cs[t] = -INFINITY;
            }
            __syncthreads();
        }
        hi = lo;
    }
    __syncthreads();

    // ---- outputs: [scores | classes | boxes | valids] all as float32 ----
    float* o_sc = out;
    float* o_cl = out + NCLS * KDET;
    float* o_bx = out + 2 * NCLS * KDET;
    float* o_va = out + 6 * NCLS * KDET;
    for (int k = tid; k < KDET; k += TPB) {
        bool valid = k < kc;
        o_sc[c * KDET + k] = valid ? ksc[k] : 0.0f;
        o_cl[c * KDET + k] = (float)c;
        o_va[c * KDET + k] = valid ? 1.0f : 0.0f;
        float4 bo;
        if (valid) { bo.x = kx1[k]; bo.y = ky1[k]; bo.z = kx2[k]; bo.w = ky2[k]; }
        else       { bo.x = 0.0f; bo.y = 0.0f; bo.z = 0.0f; bo.w = 0.0f; }
        *(float4*)(o_bx + ((size_t)(c * KDET + k)) * 4) = bo;
    }
}

extern "C" void kernel_launch(void* const* d_in, const int* in_sizes, int n_in,
                              void* d_out, int out_size, void* d_ws, size_t ws_size,
                              hipStream_t stream) {
    const float* scores = (const float*)d_in[0];   // [N, C] f32
    const float* boxes  = (const float*)d_in[1];   // [N, 4] f32
    float* out = (float*)d_out;                    // 56000 f32: scores|classes|boxes|valids

    const size_t needT = (size_t)NCLS * N_ANCH * sizeof(float);
    if (ws_size >= needT) {
        float* st = (float*)d_ws;
        const int tblocks = (N_ANCH + TROWS - 1) / TROWS;
        transpose_scores<<<tblocks, 256, 0, stream>>>(scores, st);
        nms_kernel<<<NCLS, TPB, 0, stream>>>(st, 1, 1, boxes, out);
    } else {
        // fallback: strided (uncoalesced) column reads straight from [N,C]
        nms_kernel<<<NCLS, TPB, 0, stream>>>(scores, NCLS, 0, boxes, out);
    }
}

// Round 2
// 228.618 us; speedup vs baseline: 2.3434x; 2.3434x over previous
//
#include <hip/hip_runtime.h>
#include <math.h>
#include <stdint.h>

#define N_ANCH 49104
#define NCLS 80
#define KDET 100
#define CAP 512       // candidates per chunk (top bins ~48 each; need ~110 for 100 keeps)
#define NBINS 1024
#define TPB 512
#define TROWS 128

// ---------------- transpose [N,C] -> [C,N] so per-class reads are coalesced ----------------
__global__ __launch_bounds__(256) void transpose_scores(const float* __restrict__ scores,
                                                        float* __restrict__ st) {
    __shared__ float tile[TROWS][NCLS + 1];
    const int n0 = blockIdx.x * TROWS;
    for (int i = threadIdx.x; i < TROWS * NCLS; i += blockDim.x) {
        int j = i / NCLS, c = i - j * NCLS;
        int n = n0 + j;
        tile[j][c] = (n < N_ANCH) ? scores[(size_t)n * NCLS + c] : -1.0f;
    }
    __syncthreads();
    for (int i = threadIdx.x; i < TROWS * NCLS; i += blockDim.x) {
        int c = i / TROWS, j = i - c * TROWS;
        int n = n0 + j;
        if (n < N_ANCH) st[(size_t)c * N_ANCH + n] = tile[j][c];
    }
}

// ------- one block per class: histogram chunk -> bitonic sort -> IoU bitmatrix -> mask scan -------
__global__ __launch_bounds__(TPB) void nms_kernel(const float* __restrict__ st,
                                                  const float* __restrict__ boxes,
                                                  float* __restrict__ out) {
    const int c = blockIdx.x;
    const int tid = threadIdx.x;
    const float* col = st + (size_t)c * N_ANCH;
    const float4* col4 = (const float4*)col;

    __shared__ int      hist[NBINS];
    __shared__ float4   rbox[CAP];            // rank-ordered candidate boxes
    __shared__ float    ra[CAP], rs[CAP];     // areas, scores
    __shared__ uint64_t uni[CAP * 8];         // union: sort keys (CAP u64) / bitmatrix (CAP rows x 8 words)
    __shared__ float4   kbox[KDET];
    __shared__ float    kar[KDET], ksc[KDET];
    __shared__ uint64_t lw[8];                // live words
    __shared__ int      s_cnt, s_lo, s_kc;

    uint64_t* keys = uni;
    uint64_t* smat = uni;

    // ---- pass 1: score histogram (scores > 0.05 only), coalesced float4 reads ----
    for (int b = tid; b < NBINS; b += TPB) hist[b] = 0;
    __syncthreads();
    for (int q = tid; q < N_ANCH / 4; q += TPB) {
        float4 s4 = col4[q];
        float ss[4] = {s4.x, s4.y, s4.z, s4.w};
#pragma unroll
        for (int u = 0; u < 4; u++) {
            float s = ss[u];
            if (s > 0.05f) {
                int b = (int)(s * (float)NBINS);
                b = b < 0 ? 0 : (b > NBINS - 1 ? NBINS - 1 : b);
                atomicAdd(&hist[b], 1);
            }
        }
    }
    __syncthreads();

    int kc = 0;
    int hi = NBINS;
    while (hi > 0 && kc < KDET) {
        if (tid == 0) {
            int lo = hi, tot = 0;
            while (lo > 0 && tot + hist[lo - 1] <= CAP) { lo--; tot += hist[lo]; }
            if (lo == hi) lo = hi - 1;   // oversized single bin (impossible at ~48/bin): truncate
            s_lo = lo; s_cnt = 0;
        }
        __syncthreads();
        const int lo = s_lo;

        // ---- collect chunk candidates as packed sort keys: (~score_bits)<<16 | anchor ----
        for (int q = tid; q < N_ANCH / 4; q += TPB) {
            float4 s4 = col4[q];
            float ss[4] = {s4.x, s4.y, s4.z, s4.w};
#pragma unroll
            for (int u = 0; u < 4; u++) {
                float s = ss[u];
                if (s > 0.05f) {
                    int b = (int)(s * (float)NBINS);
                    b = b < 0 ? 0 : (b > NBINS - 1 ? NBINS - 1 : b);
                    if (b >= lo && b < hi) {
                        int p = atomicAdd(&s_cnt, 1);
                        if (p < CAP) {
                            uint32_t bits = __float_as_uint(s);   // scores > 0 => bit order == value order
                            keys[p] = ((uint64_t)(~bits) << 16) | (uint64_t)(4 * q + u);
                        }
                    }
                }
            }
        }
        __syncthreads();
        const int M = min(s_cnt, CAP);
        for (int p = tid; p < CAP; p += TPB)
            if (p >= M) keys[p] = ~0ull;     // pads sort to the end
        __syncthreads();

        // ---- bitonic sort ascending (=> descending score, ascending index on ties) ----
        for (int k = 2; k <= CAP; k <<= 1) {
            for (int j = k >> 1; j > 0; j >>= 1) {
                int t = tid;                  // TPB == CAP: one compare-exchange per thread
                int ixj = t ^ j;
                if (ixj > t) {
                    uint64_t a = keys[t], b = keys[ixj];
                    bool up = ((t & k) == 0);
                    if ((a > b) == up) { keys[t] = b; keys[ixj] = a; }
                }
                __syncthreads();
            }
        }

        // ---- gather rank-ordered candidate data (boxes via L2-warm global gather) ----
        {
            int r = tid;
            if (r < M) {
                uint64_t key = keys[r];
                int n = (int)(key & 0xFFFFull);               // N_ANCH < 65536
                uint32_t bits = ~((uint32_t)(key >> 16));
                float4 bx = *(const float4*)(boxes + (size_t)n * 4);
                rbox[r] = bx;
                ra[r] = (bx.z - bx.x) * (bx.w - bx.y);
                rs[r] = __uint_as_float(bits);
            }
        }
        __syncthreads();   // keys fully consumed; uni region free for bitmatrix

        // ---- filter vs previously-kept boxes; build live words via ballot (r == tid) ----
        {
            int r = tid;
            bool alive = (r < M);
            if (alive) {
                float4 b = rbox[r];
                float arb = ra[r];
                for (int k2 = 0; k2 < kc; k2++) {
                    float4 kb = kbox[k2];
                    float ix1 = fmaxf(kb.x, b.x), iy1 = fmaxf(kb.y, b.y);
                    float ix2 = fminf(kb.z, b.z), iy2 = fminf(kb.w, b.w);
                    float inter = fmaxf(ix2 - ix1, 0.0f) * fmaxf(iy2 - iy1, 0.0f);
                    float iou = inter / (kar[k2] + arb - inter + 1e-8f);
                    if (iou > 0.5f) { alive = false; break; }
                }
            }
            uint64_t bal = __ballot(alive);
            if ((tid & 63) == 0) lw[tid >> 6] = bal;
        }
        __syncthreads();

        // ---- bitmatrix: row i (suppressor) bits over victims j > i, wave-parallel ballots ----
        {
            const int wid = tid >> 6, lane = tid & 63;
            const int MW = (M + 63) >> 6;
            for (int i = wid; i < M; i += TPB / 64) {
                float4 bi = rbox[i];          // same-address LDS broadcast
                float ari = ra[i];
                for (int w = i >> 6; w < MW; w++) {
                    int jj = (w << 6) + lane;
                    bool bit = false;
                    if (jj > i && jj < M) {
                        float4 bj = rbox[jj];
                        float ix1 = fmaxf(bi.x, bj.x), iy1 = fmaxf(bi.y, bj.y);
                        float ix2 = fminf(bi.z, bj.z), iy2 = fminf(bi.w, bj.w);
                        float inter = fmaxf(ix2 - ix1, 0.0f) * fmaxf(iy2 - iy1, 0.0f);
                        float iou = inter / (ari + ra[jj] - inter + 1e-8f);
                        bit = iou > 0.5f;
                    }
                    uint64_t bal = __ballot(bit);
                    if (lane == 0) smat[i * 8 + w] = bal;
                }
            }
        }
        __syncthreads();

        // ---- serial mask scan (thread 0): ~110 keeps x ~20 LDS ops; skips are register bit-walks ----
        if (tid == 0) {
            int kcl = kc;
            const int MW = (M + 63) >> 6;
            for (int w = 0; w < MW && kcl < KDET; w++) {
                uint64_t lv = lw[w];
                const int base = w << 6;
                while (lv) {
                    int b = __ffsll((unsigned long long)lv) - 1;
                    lv &= lv - 1;
                    int i = base + b;
                    if (i >= M) break;
                    kbox[kcl] = rbox[i];
                    kar[kcl] = ra[i];
                    ksc[kcl] = rs[i];
                    kcl++;
                    if (kcl == KDET) break;
                    lv &= ~smat[i * 8 + w];                       // suppress within current word
                    for (int ww = w + 1; ww < MW; ww++) {         // and in future words
                        uint64_t r = smat[i * 8 + ww];
                        if (r) lw[ww] &= ~r;
                    }
                }
            }
            s_kc = kcl;
        }
        __syncthreads();
        kc = s_kc;
        hi = lo;
    }

    // ---- outputs: [scores | classes | boxes | valids] as float32 ----
    float* o_sc = out;
    float* o_cl = out + NCLS * KDET;
    float* o_bx = out + 2 * NCLS * KDET;
    float* o_va = out + 6 * NCLS * KDET;
    for (int k = tid; k < KDET; k += TPB) {
        bool valid = k < kc;
        o_sc[c * KDET + k] = valid ? ksc[k] : 0.0f;
        o_cl[c * KDET + k] = (float)c;
        o_va[c * KDET + k] = valid ? 1.0f : 0.0f;
        float4 bo;
        if (valid) bo = kbox[k];
        else { bo.x = 0.0f; bo.y = 0.0f; bo.z = 0.0f; bo.w = 0.0f; }
        *(float4*)(o_bx + ((size_t)(c * KDET + k)) * 4) = bo;
    }
}

extern "C" void kernel_launch(void* const* d_in, const int* in_sizes, int n_in,
                              void* d_out, int out_size, void* d_ws, size_t ws_size,
                              hipStream_t stream) {
    const float* scores = (const float*)d_in[0];   // [N, C] f32
    const float* boxes  = (const float*)d_in[1];   // [N, 4] f32
    float* out = (float*)d_out;                    // 56000 f32: scores|classes|boxes|valids

    float* st = (float*)d_ws;                      // ws >= 80*49104*4 B (verified in round 1)
    const int tblocks = (N_ANCH + TROWS - 1) / TROWS;
    transpose_scores<<<tblocks, 256, 0, stream>>>(scores, st);
    nms_kernel<<<NCLS, TPB, 0, stream>>>(st, boxes, out);
}